// Round 8
// baseline (338.734 us; speedup 1.0000x reference)
//
#include <hip/hip_runtime.h>

typedef _Float16 f16;
typedef _Float16 half8 __attribute__((ext_vector_type(8)));
typedef _Float16 half4_t __attribute__((ext_vector_type(4)));
typedef float f32x4 __attribute__((ext_vector_type(4)));

#define T_SEQ 2048
#define B_SZ 2
#define DM 2048
#define NH 16
#define NKV 4
#define DH 128
#define NQKV 2560    // (16+4)*128
#define NALL 4736    // 2560 (qkv) + 128 (rk pad) + 2048 (gate)
#define NALLP 4864   // padded to 19*256 for the 256-row GEMM grid
#define COL_RK 2560
#define COL_G 2688
#define M_ROWS 4096  // B*T
#define WIN 1024

typedef __attribute__((address_space(1))) const unsigned int guint;
typedef __attribute__((address_space(3))) unsigned int luint;
__device__ __forceinline__ void gload16(const void* g, void* l) {
  __builtin_amdgcn_global_load_lds((guint*)g, (luint*)l, 16, 0, 0);
}

// ---------------- fp32 -> f16 elementwise ----------------
__global__ void k_cvt(const float* __restrict__ in, f16* __restrict__ out, int n) {
  int i = (blockIdx.x * 256 + threadIdx.x) * 4;
  if (i >= n) return;
  float4 v = *(const float4*)(in + i);
  half4_t o;
  o[0] = (f16)v.x; o[1] = (f16)v.y; o[2] = (f16)v.z; o[3] = (f16)v.w;
  *(half4_t*)(out + i) = o;
}

// ---------------- fp32 (K,N) -> f16 (N,K) transpose-convert ----------------
__global__ __launch_bounds__(256) void k_cvt_t(const float* __restrict__ W,
                                               f16* __restrict__ Wt, int K, int N) {
  __shared__ float tile[32][33];
  int k0 = blockIdx.x * 32, n0 = blockIdx.y * 32;
  int tx = threadIdx.x & 31, ty = threadIdx.x >> 5; // 32 x 8
#pragma unroll
  for (int r = 0; r < 32; r += 8)
    tile[ty + r][tx] = W[(size_t)(k0 + ty + r) * N + n0 + tx];
  __syncthreads();
#pragma unroll
  for (int r = 0; r < 32; r += 8)
    Wt[(size_t)(n0 + ty + r) * K + k0 + tx] = (f16)tile[tx][ty + r];
}

// ---------------- f16 [T][128] -> f16 [128][T] per matrix ----------------
__global__ __launch_bounds__(256) void k_vt(const f16* __restrict__ v, f16* __restrict__ vt) {
  __shared__ f16 tile[32][34];
  int t0 = blockIdx.x * 32, d0 = blockIdx.y * 32, m = blockIdx.z;
  int tx = threadIdx.x & 31, ty = threadIdx.x >> 5;
  const f16* src = v + (size_t)m * T_SEQ * DH;
  f16* dst = vt + (size_t)m * T_SEQ * DH;
#pragma unroll
  for (int r = 0; r < 32; r += 8)
    tile[ty + r][tx] = src[(size_t)(t0 + ty + r) * DH + d0 + tx];
  __syncthreads();
#pragma unroll
  for (int r = 0; r < 32; r += 8)
    dst[(size_t)(d0 + ty + r) * T_SEQ + t0 + tx] = tile[tx][ty + r];
}

// ======== pipelined GEMM: C[M,NALLP](f16) = A[M,K] * Bt[NALLP,K]^T ========
// BM=256, BN=128, BK=32 (one phase per K-step), 8 waves (4M x 2N), wave tile 64x64.
// TRIPLE-buffered LDS (72KB -> 2 blocks/CU), stage distance 2, vmcnt(3).
#define GEMM_PHASE3(cb, sb, nt)                                                             \
  {                                                                                         \
    char* Ab = lds + (cb) * 16384;                                                          \
    char* Bb = lds + 49152 + (cb) * 8192;                                                   \
    int koff = (nt) * 32;                                                                   \
    half8 af[4], bf[4];                                                                     \
    _Pragma("unroll")                                                                       \
    for (int i = 0; i < 4; ++i)                                                             \
      af[i] = *(const half8*)(Ab + (wm * 64 + i * 16 + fr) * 64 + xsl);                     \
    _Pragma("unroll")                                                                       \
    for (int j = 0; j < 4; ++j)                                                             \
      bf[j] = *(const half8*)(Bb + (wn * 64 + j * 16 + fr) * 64 + xsl);                     \
    gload16(Ag0 + koff, lds + (sb) * 16384 + w * 1024);                                     \
    gload16(Ag1 + koff, lds + (sb) * 16384 + 8192 + w * 1024);                              \
    gload16(Bg + koff, lds + 49152 + (sb) * 8192 + w * 1024);                               \
    __builtin_amdgcn_s_barrier();                                                           \
    __builtin_amdgcn_sched_barrier(0);                                                      \
    asm volatile("s_waitcnt lgkmcnt(0)" ::: "memory");                                      \
    __builtin_amdgcn_sched_barrier(0);                                                      \
    __builtin_amdgcn_s_setprio(1);                                                          \
    _Pragma("unroll")                                                                       \
    for (int i = 0; i < 4; ++i)                                                             \
      _Pragma("unroll")                                                                     \
      for (int j = 0; j < 4; ++j)                                                           \
        acc[i][j] = __builtin_amdgcn_mfma_f32_16x16x32_f16(af[i], bf[j], acc[i][j], 0, 0, 0); \
    __builtin_amdgcn_s_setprio(0);                                                          \
    asm volatile("s_waitcnt vmcnt(3)" ::: "memory");                                        \
    __builtin_amdgcn_s_barrier();                                                           \
    __builtin_amdgcn_sched_barrier(0);                                                      \
  }

__global__ __launch_bounds__(512, 4) void k_gemm8(const f16* __restrict__ A,
                                                  const f16* __restrict__ Bt,
                                                  f16* __restrict__ C) {
  __shared__ __align__(16) char lds[73728];
  const int K = DM;
  // bijective XCD swizzle: nwg = 38*16 = 608 = 8*76
  unsigned orig = blockIdx.y * 38u + blockIdx.x;
  unsigned swz = (orig & 7u) * 76u + (orig >> 3);
  int m0 = (int)(swz / 38u) * 256;
  int n0 = (int)(swz % 38u) * 128;
  int tid = threadIdx.x, lane = tid & 63, w = tid >> 6;
  int wm = w >> 1, wn = w & 1;
  int fr = lane & 15, fq = lane >> 4;
  int xsl = (fq ^ ((fr >> 1) & 3)) << 4;       // read-side swizzled 16B slot
  int sr = tid >> 2, ss = tid & 3;             // staging: row-in-chunk, LDS slot
  int scol = (ss ^ ((sr >> 1) & 3)) * 8;       // inverse-swizzled source col (f16)
  f32x4 acc[4][4] = {};
  const f16* Ag0 = A + (size_t)(m0 + sr) * K + scol;        // rows 0..127 of A-tile
  const f16* Ag1 = A + (size_t)(m0 + 128 + sr) * K + scol;  // rows 128..255
  const f16* Bg  = Bt + (size_t)(n0 + sr) * K + scol;       // rows 0..127 of B-tile

  // prologue: stage tiles 0 and 1 (6 loads); vmcnt(3) -> tile 0 resident
  gload16(Ag0, lds + w * 1024);
  gload16(Ag1, lds + 8192 + w * 1024);
  gload16(Bg, lds + 49152 + w * 1024);
  gload16(Ag0 + 32, lds + 16384 + w * 1024);
  gload16(Ag1 + 32, lds + 16384 + 8192 + w * 1024);
  gload16(Bg + 32, lds + 49152 + 8192 + w * 1024);
  asm volatile("s_waitcnt vmcnt(3)" ::: "memory");
  __builtin_amdgcn_s_barrier();
  __builtin_amdgcn_sched_barrier(0);

  // 64 K-phases: buffers cycle 0,1,2; final phase kt=63.
#pragma unroll 1
  for (int t3 = 0; t3 < 21; ++t3) {
    int ktb = t3 * 3;
    int n1_ = ktb + 3 <= 63 ? ktb + 3 : 63;
    int n2_ = ktb + 4 <= 63 ? ktb + 4 : 63;
    GEMM_PHASE3(0, 2, ktb + 2);
    GEMM_PHASE3(1, 0, n1_);
    GEMM_PHASE3(2, 1, n2_);
  }
  GEMM_PHASE3(0, 2, 63);  // kt=63 (redundant re-stage of tile 63: benign)

#pragma unroll
  for (int i = 0; i < 4; ++i) {
    int row = m0 + wm * 64 + i * 16 + fq * 4;
#pragma unroll
    for (int j = 0; j < 4; ++j) {
      int col = n0 + wn * 64 + j * 16 + fr;
      f16* Cp = C + (size_t)row * NALLP + col;
#pragma unroll
      for (int rr = 0; rr < 4; ++rr) Cp[(size_t)rr * NALLP] = (f16)acc[i][j][rr];
    }
  }
}

// ---------------- RMSNorm + RoPE + scale + pack q/k/v as f16 ----------------
__global__ __launch_bounds__(256) void k_postproc(
    const f16* __restrict__ CA,
    const float* __restrict__ brk, const float* __restrict__ sscal,
    f16* __restrict__ q16, f16* __restrict__ k16, f16* __restrict__ v16) {
  int row = blockIdx.x;              // b*T + t
  int b = row >> 11, t = row & 2047;
  int lane = threadIdx.x & 63, wid = threadIdx.x >> 6;
  int ridx = lane & 31;
  // 10000^(-2*ridx/64) = exp2(-ridx * log2(10000)/32)
  float inv_freq = exp2f(-(float)ridx * 0.41524101186092074f);
  float fr = (float)t * inv_freq;
  float cs = cosf(fr), sn = sinf(fr);
  float logpos = 0.6931471805599453f * __log2f(fminf((float)(t + 1), 1024.0f));
  // 1/sqrt(128) * log2(e): attention works in exp2 domain
  const float rsqrt_d_log2e = 0.08838834764831845f * 1.4426950408889634f;
  const f16* Crow = CA + (size_t)row * NALLP;
#pragma unroll
  for (int p = 0; p < 5; ++p) {
    int h = p * 4 + wid; // 0..19
    float v0 = (float)Crow[h * 128 + lane];
    float v1 = (float)Crow[h * 128 + 64 + lane];
    float ss = v0 * v0 + v1 * v1;
#pragma unroll
    for (int m = 1; m < 64; m <<= 1) ss += __shfl_xor(ss, m);
    float rms = rsqrtf(ss * (1.0f / 128.0f) + 1e-6f);
    v0 *= rms; v1 *= rms;
    if (h < NH) {
      float part = __shfl_xor(v1, 32);
      float vr = (lane < 32) ? (v1 * cs + part * sn) : (v1 * cs - part * sn);
      float scale = sscal[h] * logpos * rsqrt_d_log2e;
      size_t qb = ((size_t)(b * NH + h) * T_SEQ + t) * DH;
      q16[qb + lane]      = (f16)(v0 * scale);
      q16[qb + 64 + lane] = (f16)(vr * scale);
    } else {
      int hk = h - NH;
      size_t kb = ((size_t)(b * NKV + hk) * T_SEQ + t) * DH;
      k16[kb + lane]      = (f16)v0;  // tied kv
      v16[kb + lane]      = (f16)v0;  // tied kv
      v16[kb + 64 + lane] = (f16)v1;  // v
    }
  }
  if (wid == 0) {
    float kr = (float)Crow[COL_RK + lane] + brk[lane];
    float part = __shfl_xor(kr, 32);
    float vr = (lane < 32) ? (kr * cs + part * sn) : (kr * cs - part * sn);
    f16 hv = (f16)vr;
#pragma unroll
    for (int hk = 0; hk < NKV; ++hk)
      k16[((size_t)(b * NKV + hk) * T_SEQ + t) * DH + 64 + lane] = hv;
  }
}

// ---------------- sliding-window flash attention + silu(g) epilogue ----------------
// BQ=64 (4 waves x 16 q-rows), KV tile 64, SINGLE-buffered K/V, 40KB LDS ->
// 4 blocks/CU (grid 1024 = exactly 4x256, all resident): cross-block TLP covers
// the stage latency (m114 mechanism) — measured better than 2/CU dbuf (r2 vs r5-7).
// K at 0 ([64][128] swz), V^T at 16384 ([128][64] swz), P at 32768 (per-wave 2KB).
// NOTE: launch_bounds min-waves MUST stay low — (512,6) capped VGPRs at 40 and
// spilled the o[] accumulator to scratch (440MB fetch, 2.3x slowdown, round 3).
__global__ __launch_bounds__(256, 2) void k_attn(
    const f16* __restrict__ q16, const f16* __restrict__ k16, const f16* __restrict__ vt16,
    const f16* __restrict__ gA, float* __restrict__ out) {
  __shared__ __align__(16) char lds[40960];
  int bx = blockIdx.x;
  int qt = (bx & 1) ? (31 - (bx >> 1)) : (bx >> 1);  // alternate light/heavy blocks
  int h = blockIdx.y, b = blockIdx.z, hk = h >> 2;
  int tid = threadIdx.x, lane = tid & 63, w = tid >> 6;  // w 0..3
  int i0 = qt * 64, iw = i0 + w * 16;
  int fr = lane & 15, fq = lane >> 4;

  char* Psb = lds + 32768 + w * 2048;

  const f16* qbase = q16 + ((size_t)(b * NH + h) * T_SEQ + iw + fr) * DH;
  half8 qf[4];
#pragma unroll
  for (int kb = 0; kb < 4; ++kb) qf[kb] = *(const half8*)&qbase[kb * 32 + fq * 8];

  f32x4 o[8] = {};
  float mrow[4] = {-1e30f, -1e30f, -1e30f, -1e30f};
  float lrow[4] = {0.f, 0.f, 0.f, 0.f};

  const f16* kg = k16 + (size_t)(b * NKV + hk) * T_SEQ * DH;   // [T][128]
  const f16* vg = vt16 + (size_t)(b * NKV + hk) * T_SEQ * DH;  // [128][T]

  int jt0 = qt >= 16 ? qt - 16 : 0;

  for (int jt = jt0; jt <= qt; ++jt) {
    int j0 = jt * 64;
    // ---- stage K (16KB) + V^T (16KB); inverse-swizzled source, linear LDS dest.
    // HW writes wave-uniform base + lane*16 => byte o = i*4096 + tid*16.
#pragma unroll
    for (int i = 0; i < 4; ++i) {
      int r = i * 16 + (tid >> 4);                 // K row for this lane's 16B
      int c = ((tid & 15) ^ (r & 7)) * 8;
      gload16(kg + (size_t)(j0 + r) * DH + c, lds + i * 4096 + w * 1024);
    }
#pragma unroll
    for (int i = 0; i < 4; ++i) {
      int r = i * 32 + (tid >> 3);                 // V^T row
      int c = ((tid & 7) ^ (r & 7)) * 8;
      gload16(vg + (size_t)r * T_SEQ + j0 + c, lds + 16384 + i * 4096 + w * 1024);
    }
    asm volatile("s_waitcnt vmcnt(0)" ::: "memory");
    __syncthreads();   // tiles resident for all waves

    // ---- S = Q K^T (16 q-rows x 64 keys per wave) ----
    f32x4 s[4] = {};
    __builtin_amdgcn_s_setprio(1);
#pragma unroll
    for (int nf = 0; nf < 4; ++nf) {
      int row = nf * 16 + fr;
      int sw = fr & 7;
#pragma unroll
      for (int kb = 0; kb < 4; ++kb) {
        half8 bfv = *(const half8*)(lds + row * 256 + ((((kb << 2) | fq) ^ sw) << 4));
        s[nf] = __builtin_amdgcn_mfma_f32_16x16x32_f16(qf[kb], bfv, s[nf], 0, 0, 0);
      }
    }
    __builtin_amdgcn_s_setprio(0);
    // ---- masking: only diagonal and window-edge tiles ----
    int il = (w << 4) + (fq << 2);
    if (jt == qt) {
#pragma unroll
      for (int nf = 0; nf < 4; ++nf) {
        int jo = nf * 16 + fr;
#pragma unroll
        for (int r = 0; r < 4; ++r)
          if (jo > il + r) s[nf][r] = -3e38f;
      }
    } else if (qt >= 16 && jt == jt0) {
#pragma unroll
      for (int nf = 0; nf < 4; ++nf) {
        int jo = nf * 16 + fr;
#pragma unroll
        for (int r = 0; r < 4; ++r)
          if (jo < il + r) s[nf][r] = -3e38f;
      }
    }
    // ---- online softmax (exp2 domain), defer-max rescale ----
    float tm[4];
#pragma unroll
    for (int r = 0; r < 4; ++r)
      tm[r] = fmaxf(fmaxf(s[0][r], s[1][r]), fmaxf(s[2][r], s[3][r]));
#pragma unroll
    for (int r = 0; r < 4; ++r) {
      tm[r] = fmaxf(tm[r], __shfl_xor(tm[r], 1));
      tm[r] = fmaxf(tm[r], __shfl_xor(tm[r], 2));
      tm[r] = fmaxf(tm[r], __shfl_xor(tm[r], 4));
      tm[r] = fmaxf(tm[r], __shfl_xor(tm[r], 8));
    }
    bool need = false;
#pragma unroll
    for (int r = 0; r < 4; ++r) need = need || (tm[r] > mrow[r] + 8.0f);
    if (__any(need)) {
#pragma unroll
      for (int r = 0; r < 4; ++r) {
        float mn = fmaxf(mrow[r], tm[r]);
        float sc = exp2f(mrow[r] - mn);
        mrow[r] = mn;
        lrow[r] *= sc;
#pragma unroll
        for (int of = 0; of < 8; ++of) o[of][r] *= sc;
      }
    }
    float ls[4] = {0.f, 0.f, 0.f, 0.f};
#pragma unroll
    for (int nf = 0; nf < 4; ++nf)
#pragma unroll
      for (int r = 0; r < 4; ++r) {
        float pv = exp2f(s[nf][r] - mrow[r]);
        s[nf][r] = pv;
        ls[r] += pv;
      }
#pragma unroll
    for (int r = 0; r < 4; ++r) {
      float t2 = ls[r];
      t2 += __shfl_xor(t2, 1); t2 += __shfl_xor(t2, 2);
      t2 += __shfl_xor(t2, 4); t2 += __shfl_xor(t2, 8);
      lrow[r] += t2;
    }
    // ---- P -> per-wave LDS (swizzled), wave-local ordering only ----
#pragma unroll
    for (int nf = 0; nf < 4; ++nf) {
      int sbase = (nf << 1) + (fr >> 3);
      int boff = (fr & 7) << 1;
#pragma unroll
      for (int r = 0; r < 4; ++r) {
        int q = (fq << 2) + r;
        *(f16*)(Psb + q * 128 + ((sbase ^ (q & 7)) << 4) + boff) = (f16)s[nf][r];
      }
    }
    asm volatile("s_waitcnt lgkmcnt(0)" ::: "memory");
    __builtin_amdgcn_sched_barrier(0);
    half8 pf0 = *(const half8*)(Psb + fr * 128 + (((fq) ^ (fr & 7)) << 4));
    half8 pf1 = *(const half8*)(Psb + fr * 128 + (((4 | fq) ^ (fr & 7)) << 4));
    // ---- O += P V ----
    __builtin_amdgcn_s_setprio(1);
#pragma unroll
    for (int of = 0; of < 8; ++of) {
      int vrow0 = of * 16 + fr;
      int sw = fr & 7;
      half8 v0 = *(const half8*)(lds + 16384 + vrow0 * 128 + ((fq ^ sw) << 4));
      half8 v1 = *(const half8*)(lds + 16384 + vrow0 * 128 + (((4 | fq) ^ sw) << 4));
      o[of] = __builtin_amdgcn_mfma_f32_16x16x32_f16(pf0, v0, o[of], 0, 0, 0);
      o[of] = __builtin_amdgcn_mfma_f32_16x16x32_f16(pf1, v1, o[of], 0, 0, 0);
    }
    __builtin_amdgcn_s_setprio(0);
    __syncthreads();   // all waves done reading K/V before next stage overwrites
  }
  // ---- epilogue: normalize + silu(g), write (B,T,H,D) ----
  const f16* gb = gA + ((size_t)(b * T_SEQ) + iw) * NALLP + COL_G + h * DH;
  float* ob = out + ((size_t)(b * T_SEQ) + iw) * DM + h * DH;
#pragma unroll
  for (int r = 0; r < 4; ++r) {
    float inv = 1.0f / lrow[r];
    int ir = fq * 4 + r;
#pragma unroll
    for (int of = 0; of < 8; ++of) {
      int d = of * 16 + fr;
      float gv = (float)gb[(size_t)ir * NALLP + d];
      float sig = gv / (1.0f + expf(-gv));
      ob[(size_t)ir * DM + d] = o[of][r] * inv * sig;
    }
  }
}

extern "C" void kernel_launch(void* const* d_in, const int* in_sizes, int n_in,
                              void* d_out, int out_size, void* d_ws, size_t ws_size,
                              hipStream_t stream) {
  const float* x     = (const float*)d_in[0];
  const float* Wqkv  = (const float*)d_in[1];
  const float* Wrk   = (const float*)d_in[2];
  const float* brk   = (const float*)d_in[3];
  const float* sscal = (const float*)d_in[4];
  const float* Wg    = (const float*)d_in[5];
  float* out = (float*)d_out;
  char* ws = (char*)d_ws;
  size_t off = 0;
  auto alloc = [&](size_t bytes) -> void* {
    void* p = ws + off;
    off += (bytes + 255) & ~(size_t)255;
    return p;
  };
  f16* x16     = (f16*)alloc((size_t)M_ROWS * DM * 2);
  f16* BtAll   = (f16*)alloc((size_t)NALLP * DM * 2);
  f16* CAll    = (f16*)alloc((size_t)M_ROWS * NALLP * 2);
  f16* q16     = (f16*)alloc((size_t)B_SZ * NH * T_SEQ * DH * 2);
  f16* k16     = (f16*)alloc((size_t)B_SZ * NKV * T_SEQ * DH * 2);
  f16* v16     = (f16*)alloc((size_t)B_SZ * NKV * T_SEQ * DH * 2);
  f16* vt16    = (f16*)alloc((size_t)B_SZ * NKV * T_SEQ * DH * 2);

  k_cvt<<<(M_ROWS * DM / 4 + 255) / 256, 256, 0, stream>>>(x, x16, M_ROWS * DM);
  k_cvt_t<<<dim3(DM / 32, NQKV / 32), 256, 0, stream>>>(Wqkv, BtAll, DM, NQKV);
  k_cvt_t<<<dim3(DM / 32, 64 / 32), 256, 0, stream>>>(Wrk, BtAll + (size_t)COL_RK * DM, DM, 64);
  k_cvt_t<<<dim3(DM / 32, DM / 32), 256, 0, stream>>>(Wg, BtAll + (size_t)COL_G * DM, DM, DM);

  k_gemm8<<<dim3(NALLP / 128, M_ROWS / 256), 512, 0, stream>>>(x16, BtAll, CAll);

  k_postproc<<<M_ROWS, 256, 0, stream>>>(CAll, brk, sscal, q16, k16, v16);
  k_vt<<<dim3(T_SEQ / 32, DH / 32, B_SZ * NKV), 256, 0, stream>>>(v16, vt16);

  k_attn<<<dim3(T_SEQ / 64, NH, B_SZ), 256, 0, stream>>>(q16, k16, vt16, CAll, out);
}

// Round 9
// 304.931 us; speedup vs baseline: 1.1109x; 1.1109x over previous
//
#include <hip/hip_runtime.h>

typedef _Float16 f16;
typedef _Float16 half8 __attribute__((ext_vector_type(8)));
typedef _Float16 half4_t __attribute__((ext_vector_type(4)));
typedef float f32x4 __attribute__((ext_vector_type(4)));

#define T_SEQ 2048
#define B_SZ 2
#define DM 2048
#define NH 16
#define NKV 4
#define DH 128
#define NQKV 2560    // (16+4)*128
#define NALL 4736    // 2560 (qkv) + 128 (rk pad) + 2048 (gate)
#define NALLP 4864   // padded to 19*256 for the 256-row GEMM grid
#define COL_RK 2560
#define COL_G 2688
#define M_ROWS 4096  // B*T
#define WIN 1024

typedef __attribute__((address_space(1))) const unsigned int guint;
typedef __attribute__((address_space(3))) unsigned int luint;
__device__ __forceinline__ void gload16(const void* g, void* l) {
  __builtin_amdgcn_global_load_lds((guint*)g, (luint*)l, 16, 0, 0);
}

// ---------------- fp32 -> f16 elementwise ----------------
__global__ void k_cvt(const float* __restrict__ in, f16* __restrict__ out, int n) {
  int i = (blockIdx.x * 256 + threadIdx.x) * 4;
  if (i >= n) return;
  float4 v = *(const float4*)(in + i);
  half4_t o;
  o[0] = (f16)v.x; o[1] = (f16)v.y; o[2] = (f16)v.z; o[3] = (f16)v.w;
  *(half4_t*)(out + i) = o;
}

// ---------------- fp32 (K,N) -> f16 (N,K) transpose-convert ----------------
__global__ __launch_bounds__(256) void k_cvt_t(const float* __restrict__ W,
                                               f16* __restrict__ Wt, int K, int N) {
  __shared__ float tile[32][33];
  int k0 = blockIdx.x * 32, n0 = blockIdx.y * 32;
  int tx = threadIdx.x & 31, ty = threadIdx.x >> 5; // 32 x 8
#pragma unroll
  for (int r = 0; r < 32; r += 8)
    tile[ty + r][tx] = W[(size_t)(k0 + ty + r) * N + n0 + tx];
  __syncthreads();
#pragma unroll
  for (int r = 0; r < 32; r += 8)
    Wt[(size_t)(n0 + ty + r) * K + k0 + tx] = (f16)tile[tx][ty + r];
}

// ---------------- f16 [T][128] -> f16 [128][T] per matrix ----------------
__global__ __launch_bounds__(256) void k_vt(const f16* __restrict__ v, f16* __restrict__ vt) {
  __shared__ f16 tile[32][34];
  int t0 = blockIdx.x * 32, d0 = blockIdx.y * 32, m = blockIdx.z;
  int tx = threadIdx.x & 31, ty = threadIdx.x >> 5;
  const f16* src = v + (size_t)m * T_SEQ * DH;
  f16* dst = vt + (size_t)m * T_SEQ * DH;
#pragma unroll
  for (int r = 0; r < 32; r += 8)
    tile[ty + r][tx] = src[(size_t)(t0 + ty + r) * DH + d0 + tx];
  __syncthreads();
#pragma unroll
  for (int r = 0; r < 32; r += 8)
    dst[(size_t)(d0 + ty + r) * T_SEQ + t0 + tx] = tile[tx][ty + r];
}

// ======== pipelined GEMM: C[M,NALLP](f16) = A[M,K] * Bt[NALLP,K]^T ========
// BM=256, BN=128, BK=32, 4 waves (2M x 2N), WAVE TILE 128x64 (acc[8][4], 128 VGPR).
// B-frags register-resident across the K-tile's 2 phases: ds_read:MFMA = 6:16/phase avg.
// TRIPLE-buffered LDS (3 x 24KB = 72KB -> 2 blocks/CU), stage distance 2.
// vmcnt(6) ONCE per K-tile (ph1 end): kt+1's 6 loads land, kt+2's 6 stay in flight.
// Bank swizzle: 16B-slot ^= (row>>1)&3 on gload SOURCE + ds_read addr (dest linear).
#define GEMM_PHASE(cb, sb, nt, ph)                                                     \
  {                                                                                    \
    char* Ab = lds + (cb) * 24576;                                                     \
    char* Bb = lds + (cb) * 24576 + 16384;                                             \
    half8 af[4];                                                                       \
    _Pragma("unroll")                                                                  \
    for (int i = 0; i < 4; ++i)                                                        \
      af[i] = *(const half8*)(Ab + (wm * 128 + (ph) * 64 + i * 16 + fr) * 64 + xsl);   \
    if ((ph) == 0) {                                                                   \
      _Pragma("unroll")                                                                \
      for (int j = 0; j < 4; ++j)                                                      \
        bfr[j] = *(const half8*)(Bb + (wn * 64 + j * 16 + fr) * 64 + xsl);             \
    }                                                                                  \
    {                                                                                  \
      char* Sb = lds + (sb) * 24576;                                                   \
      int koff = (nt) * 32;                                                            \
      if ((ph) == 0) {                                                                 \
        gload16(Ag + koff, Sb + tid * 16);                                             \
        gload16(Ag + (size_t)64 * DM + koff, Sb + 4096 + tid * 16);                    \
        gload16(Ag + (size_t)128 * DM + koff, Sb + 8192 + tid * 16);                   \
      } else {                                                                         \
        gload16(Ag + (size_t)192 * DM + koff, Sb + 12288 + tid * 16);                  \
        gload16(Bg + koff, Sb + 16384 + tid * 16);                                     \
        gload16(Bg + (size_t)64 * DM + koff, Sb + 20480 + tid * 16);                   \
      }                                                                                \
    }                                                                                  \
    __builtin_amdgcn_s_barrier();                                                      \
    __builtin_amdgcn_sched_barrier(0);                                                 \
    asm volatile("s_waitcnt lgkmcnt(0)" ::: "memory");                                 \
    __builtin_amdgcn_sched_barrier(0);                                                 \
    __builtin_amdgcn_s_setprio(1);                                                     \
    _Pragma("unroll")                                                                  \
    for (int i = 0; i < 4; ++i)                                                        \
      _Pragma("unroll")                                                                \
      for (int j = 0; j < 4; ++j)                                                      \
        acc[(ph) * 4 + i][j] = __builtin_amdgcn_mfma_f32_16x16x32_f16(                 \
            af[i], bfr[j], acc[(ph) * 4 + i][j], 0, 0, 0);                             \
    __builtin_amdgcn_s_setprio(0);                                                     \
    if ((ph) == 1) asm volatile("s_waitcnt vmcnt(6)" ::: "memory");                    \
    __builtin_amdgcn_s_barrier();                                                      \
    __builtin_amdgcn_sched_barrier(0);                                                 \
  }

#define GEMM_KT(cb, sb, nt) GEMM_PHASE(cb, sb, nt, 0) GEMM_PHASE(cb, sb, nt, 1)

__global__ __launch_bounds__(256, 2) void k_gemm8(const f16* __restrict__ A,
                                                  const f16* __restrict__ Bt,
                                                  f16* __restrict__ C) {
  __shared__ __align__(16) char lds[73728];
  // bijective XCD swizzle: nwg = 38*16 = 608 = 8*76
  unsigned orig = blockIdx.y * 38u + blockIdx.x;
  unsigned swz = (orig & 7u) * 76u + (orig >> 3);
  int m0 = (int)(swz / 38u) * 256;
  int n0 = (int)(swz % 38u) * 128;
  int tid = threadIdx.x, lane = tid & 63, w = tid >> 6;  // 4 waves
  int wm = w >> 1, wn = w & 1;                           // 2M x 2N
  int fr = lane & 15, fq = lane >> 4;
  int xsl = (fq ^ ((fr >> 1) & 3)) << 4;       // read-side swizzled 16B slot
  int scol = ((tid & 3) ^ ((tid >> 3) & 3)) * 8;  // inverse-swizzled source col (f16)
  f32x4 acc[8][4] = {};
  half8 bfr[4];
  const f16* Ag = A + (size_t)(m0 + (tid >> 2)) * DM + scol;   // +L*64 rows per chunk
  const f16* Bg = Bt + (size_t)(n0 + (tid >> 2)) * DM + scol;

  // prologue: stage kt0 -> slot0, kt1 -> slot1 (12 loads); vmcnt(6) -> kt0 resident
  gload16(Ag, lds + tid * 16);
  gload16(Ag + (size_t)64 * DM, lds + 4096 + tid * 16);
  gload16(Ag + (size_t)128 * DM, lds + 8192 + tid * 16);
  gload16(Ag + (size_t)192 * DM, lds + 12288 + tid * 16);
  gload16(Bg, lds + 16384 + tid * 16);
  gload16(Bg + (size_t)64 * DM, lds + 20480 + tid * 16);
  gload16(Ag + 32, lds + 24576 + tid * 16);
  gload16(Ag + (size_t)64 * DM + 32, lds + 24576 + 4096 + tid * 16);
  gload16(Ag + (size_t)128 * DM + 32, lds + 24576 + 8192 + tid * 16);
  gload16(Ag + (size_t)192 * DM + 32, lds + 24576 + 12288 + tid * 16);
  gload16(Bg + 32, lds + 24576 + 16384 + tid * 16);
  gload16(Bg + (size_t)64 * DM + 32, lds + 24576 + 20480 + tid * 16);
  asm volatile("s_waitcnt vmcnt(6)" ::: "memory");
  __builtin_amdgcn_s_barrier();
  __builtin_amdgcn_sched_barrier(0);

  // 64 K-tiles; slots cycle 0,1,2; stage distance 2; final kt=63.
#pragma unroll 1
  for (int t3 = 0; t3 < 21; ++t3) {
    int kb0 = t3 * 3;
    int n3 = kb0 + 4 <= 63 ? kb0 + 4 : 63;
    GEMM_KT(0, 2, kb0 + 2);
    GEMM_KT(1, 0, kb0 + 3);
    GEMM_KT(2, 1, n3);
  }
  GEMM_KT(0, 2, 63);  // kt=63 (redundant re-stage: lands in unread slot, benign)

#pragma unroll
  for (int ii = 0; ii < 8; ++ii) {
    int row = m0 + wm * 128 + (ii >> 2) * 64 + (ii & 3) * 16 + fq * 4;
#pragma unroll
    for (int j = 0; j < 4; ++j) {
      int col = n0 + wn * 64 + j * 16 + fr;
      f16* Cp = C + (size_t)row * NALLP + col;
#pragma unroll
      for (int rr = 0; rr < 4; ++rr) Cp[(size_t)rr * NALLP] = (f16)acc[ii][j][rr];
    }
  }
}

// ---------------- RMSNorm + RoPE + scale + pack q/k/v as f16 ----------------
__global__ __launch_bounds__(256) void k_postproc(
    const f16* __restrict__ CA,
    const float* __restrict__ brk, const float* __restrict__ sscal,
    f16* __restrict__ q16, f16* __restrict__ k16, f16* __restrict__ v16) {
  int row = blockIdx.x;              // b*T + t
  int b = row >> 11, t = row & 2047;
  int lane = threadIdx.x & 63, wid = threadIdx.x >> 6;
  int ridx = lane & 31;
  // 10000^(-2*ridx/64) = exp2(-ridx * log2(10000)/32)
  float inv_freq = exp2f(-(float)ridx * 0.41524101186092074f);
  float fr = (float)t * inv_freq;
  float cs = cosf(fr), sn = sinf(fr);
  float logpos = 0.6931471805599453f * __log2f(fminf((float)(t + 1), 1024.0f));
  // 1/sqrt(128) * log2(e): attention works in exp2 domain
  const float rsqrt_d_log2e = 0.08838834764831845f * 1.4426950408889634f;
  const f16* Crow = CA + (size_t)row * NALLP;
#pragma unroll
  for (int p = 0; p < 5; ++p) {
    int h = p * 4 + wid; // 0..19
    float v0 = (float)Crow[h * 128 + lane];
    float v1 = (float)Crow[h * 128 + 64 + lane];
    float ss = v0 * v0 + v1 * v1;
#pragma unroll
    for (int m = 1; m < 64; m <<= 1) ss += __shfl_xor(ss, m);
    float rms = rsqrtf(ss * (1.0f / 128.0f) + 1e-6f);
    v0 *= rms; v1 *= rms;
    if (h < NH) {
      float part = __shfl_xor(v1, 32);
      float vr = (lane < 32) ? (v1 * cs + part * sn) : (v1 * cs - part * sn);
      float scale = sscal[h] * logpos * rsqrt_d_log2e;
      size_t qb = ((size_t)(b * NH + h) * T_SEQ + t) * DH;
      q16[qb + lane]      = (f16)(v0 * scale);
      q16[qb + 64 + lane] = (f16)(vr * scale);
    } else {
      int hk = h - NH;
      size_t kb = ((size_t)(b * NKV + hk) * T_SEQ + t) * DH;
      k16[kb + lane]      = (f16)v0;  // tied kv
      v16[kb + lane]      = (f16)v0;  // tied kv
      v16[kb + 64 + lane] = (f16)v1;  // v
    }
  }
  if (wid == 0) {
    float kr = (float)Crow[COL_RK + lane] + brk[lane];
    float part = __shfl_xor(kr, 32);
    float vr = (lane < 32) ? (kr * cs + part * sn) : (kr * cs - part * sn);
    f16 hv = (f16)vr;
#pragma unroll
    for (int hk = 0; hk < NKV; ++hk)
      k16[((size_t)(b * NKV + hk) * T_SEQ + t) * DH + 64 + lane] = hv;
  }
}

// ---------------- sliding-window flash attention + silu(g) epilogue ----------------
// BQ=64 (4 waves x 16 q-rows), KV tile 64, single-buffered, 40KB LDS -> 4 blocks/CU.
// SWAPPED QK^T: s = mfma(K, Q) => lane holds 16 S-values for ONE q-row (q = fr).
// Row max/sum = in-register tree + 2 shfl (over the 4 duplicate fq-lanes);
// P stored via 4 x ds_write_b64 (lane owns k = nf*16+4*fq .. +3 of row q=fr).
// O layout (from PV) has q = fq*4+r, so rescale/epilogue gather scale/1/l via 4 shfl.
// NOTE: launch_bounds min-waves MUST stay low — (512,6) capped VGPRs at 40 and
// spilled the o[] accumulator to scratch (440MB fetch, 2.3x slowdown, round 3).
__global__ __launch_bounds__(256, 2) void k_attn(
    const f16* __restrict__ q16, const f16* __restrict__ k16, const f16* __restrict__ vt16,
    const f16* __restrict__ gA, float* __restrict__ out) {
  __shared__ __align__(16) char lds[40960];
  int bx = blockIdx.x;
  int qt = (bx & 1) ? (31 - (bx >> 1)) : (bx >> 1);  // alternate light/heavy blocks
  int h = blockIdx.y, b = blockIdx.z, hk = h >> 2;
  int tid = threadIdx.x, lane = tid & 63, w = tid >> 6;  // w 0..3
  int i0 = qt * 64, iw = i0 + w * 16;
  int fr = lane & 15, fq = lane >> 4;

  char* Psb = lds + 32768 + w * 2048;

  const f16* qbase = q16 + ((size_t)(b * NH + h) * T_SEQ + iw + fr) * DH;
  half8 qf[4];
#pragma unroll
  for (int kb = 0; kb < 4; ++kb) qf[kb] = *(const half8*)&qbase[kb * 32 + fq * 8];

  f32x4 o[8] = {};
  float mrow = -1e30f, lrow = 0.f;

  const f16* kg = k16 + (size_t)(b * NKV + hk) * T_SEQ * DH;   // [T][128]
  const f16* vg = vt16 + (size_t)(b * NKV + hk) * T_SEQ * DH;  // [128][T]

  int jt0 = qt >= 16 ? qt - 16 : 0;

  for (int jt = jt0; jt <= qt; ++jt) {
    int j0 = jt * 64;
    // ---- stage K (16KB) + V^T (16KB); inverse-swizzled source, linear LDS dest ----
#pragma unroll
    for (int i = 0; i < 4; ++i) {
      int r = i * 16 + (tid >> 4);                 // K row for this lane's 16B
      int c = ((tid & 15) ^ (r & 7)) * 8;
      gload16(kg + (size_t)(j0 + r) * DH + c, lds + i * 4096 + w * 1024);
    }
#pragma unroll
    for (int i = 0; i < 4; ++i) {
      int r = i * 32 + (tid >> 3);                 // V^T row
      int c = ((tid & 7) ^ (r & 7)) * 8;
      gload16(vg + (size_t)r * T_SEQ + j0 + c, lds + 16384 + i * 4096 + w * 1024);
    }
    asm volatile("s_waitcnt vmcnt(0)" ::: "memory");
    __syncthreads();   // tiles resident for all waves

    // ---- S^T = K Q^T (swapped): lane (fr,fq) reg[nf][r] = S[key=nf*16+4fq+r][q=fr] ----
    f32x4 s[4] = {};
    __builtin_amdgcn_s_setprio(1);
#pragma unroll
    for (int nf = 0; nf < 4; ++nf) {
      int row = nf * 16 + fr;
      int sw = fr & 7;
#pragma unroll
      for (int kb = 0; kb < 4; ++kb) {
        half8 kfv = *(const half8*)(lds + row * 256 + ((((kb << 2) | fq) ^ sw) << 4));
        s[nf] = __builtin_amdgcn_mfma_f32_16x16x32_f16(kfv, qf[kb], s[nf], 0, 0, 0);
      }
    }
    __builtin_amdgcn_s_setprio(0);
    // ---- masking (key from m-side, q from n-side) ----
    int ql = (w << 4) + fr;            // q local to the 64-row q-block
    if (jt == qt) {                    // diagonal tile: mask key > q
#pragma unroll
      for (int nf = 0; nf < 4; ++nf) {
        int kbase = nf * 16 + (fq << 2);
#pragma unroll
        for (int r = 0; r < 4; ++r)
          if (kbase + r > ql) s[nf][r] = -3e38f;
      }
    } else if (qt >= 16 && jt == jt0) {  // window edge: mask key < q
#pragma unroll
      for (int nf = 0; nf < 4; ++nf) {
        int kbase = nf * 16 + (fq << 2);
#pragma unroll
        for (int r = 0; r < 4; ++r)
          if (kbase + r < ql) s[nf][r] = -3e38f;
      }
    }
    // ---- online softmax, lane-local (q = fr); defer-max rescale ----
    float a0 = fmaxf(fmaxf(s[0][0], s[0][1]), fmaxf(s[0][2], s[0][3]));
    float a1 = fmaxf(fmaxf(s[1][0], s[1][1]), fmaxf(s[1][2], s[1][3]));
    float a2 = fmaxf(fmaxf(s[2][0], s[2][1]), fmaxf(s[2][2], s[2][3]));
    float a3 = fmaxf(fmaxf(s[3][0], s[3][1]), fmaxf(s[3][2], s[3][3]));
    float tm = fmaxf(fmaxf(a0, a1), fmaxf(a2, a3));
    tm = fmaxf(tm, __shfl_xor(tm, 16));
    tm = fmaxf(tm, __shfl_xor(tm, 32));
    if (__any(tm > mrow + 8.0f)) {
      float mn = fmaxf(mrow, tm);
      float sc = exp2f(mrow - mn);
      mrow = mn;
      lrow *= sc;
      // gather scale for O rows (O row q = fq*4+r lives at softmax lane fr=q)
      float s0 = __shfl(sc, (fq << 2) + 0);
      float s1 = __shfl(sc, (fq << 2) + 1);
      float s2 = __shfl(sc, (fq << 2) + 2);
      float s3 = __shfl(sc, (fq << 2) + 3);
#pragma unroll
      for (int of = 0; of < 8; ++of) {
        o[of][0] *= s0; o[of][1] *= s1; o[of][2] *= s2; o[of][3] *= s3;
      }
    }
#pragma unroll
    for (int nf = 0; nf < 4; ++nf)
#pragma unroll
      for (int r = 0; r < 4; ++r)
        s[nf][r] = exp2f(s[nf][r] - mrow);
    float l0 = (s[0][0] + s[0][1]) + (s[0][2] + s[0][3]);
    float l1 = (s[1][0] + s[1][1]) + (s[1][2] + s[1][3]);
    float l2 = (s[2][0] + s[2][1]) + (s[2][2] + s[2][3]);
    float l3 = (s[3][0] + s[3][1]) + (s[3][2] + s[3][3]);
    float ls = (l0 + l1) + (l2 + l3);
    ls += __shfl_xor(ls, 16);
    ls += __shfl_xor(ls, 32);
    lrow += ls;
    // ---- P -> per-wave LDS: 4 x b64 (row q=fr, k = nf*16+4fq .. +3), swizzled ----
#pragma unroll
    for (int nf = 0; nf < 4; ++nf) {
      half4_t p4;
      p4[0] = (f16)s[nf][0]; p4[1] = (f16)s[nf][1];
      p4[2] = (f16)s[nf][2]; p4[3] = (f16)s[nf][3];
      int sl = ((nf << 1) + (fq >> 1)) ^ (fr & 7);
      *(half4_t*)(Psb + fr * 128 + (sl << 4) + ((fq & 1) << 3)) = p4;
    }
    asm volatile("s_waitcnt lgkmcnt(0)" ::: "memory");
    __builtin_amdgcn_sched_barrier(0);
    half8 pf0 = *(const half8*)(Psb + fr * 128 + (((fq) ^ (fr & 7)) << 4));
    half8 pf1 = *(const half8*)(Psb + fr * 128 + (((4 | fq) ^ (fr & 7)) << 4));
    // ---- O += P V ----
    __builtin_amdgcn_s_setprio(1);
#pragma unroll
    for (int of = 0; of < 8; ++of) {
      int vrow0 = of * 16 + fr;
      int sw = fr & 7;
      half8 v0 = *(const half8*)(lds + 16384 + vrow0 * 128 + ((fq ^ sw) << 4));
      half8 v1 = *(const half8*)(lds + 16384 + vrow0 * 128 + (((4 | fq) ^ sw) << 4));
      o[of] = __builtin_amdgcn_mfma_f32_16x16x32_f16(pf0, v0, o[of], 0, 0, 0);
      o[of] = __builtin_amdgcn_mfma_f32_16x16x32_f16(pf1, v1, o[of], 0, 0, 0);
    }
    __builtin_amdgcn_s_setprio(0);
    __syncthreads();   // all waves done reading K/V before next stage overwrites
  }
  // ---- epilogue: normalize (gather 1/l per O-row) + silu(g), write (B,T,H,D) ----
  float rinv = 1.0f / lrow;
  float iv0 = __shfl(rinv, (fq << 2) + 0);
  float iv1 = __shfl(rinv, (fq << 2) + 1);
  float iv2 = __shfl(rinv, (fq << 2) + 2);
  float iv3 = __shfl(rinv, (fq << 2) + 3);
  float ivv[4] = {iv0, iv1, iv2, iv3};
  const f16* gb = gA + ((size_t)(b * T_SEQ) + iw) * NALLP + COL_G + h * DH;
  float* ob = out + ((size_t)(b * T_SEQ) + iw) * DM + h * DH;
#pragma unroll
  for (int r = 0; r < 4; ++r) {
    int ir = fq * 4 + r;
#pragma unroll
    for (int of = 0; of < 8; ++of) {
      int d = of * 16 + fr;
      float gv = (float)gb[(size_t)ir * NALLP + d];
      float sig = gv / (1.0f + expf(-gv));
      ob[(size_t)ir * DM + d] = o[of][r] * ivv[r] * sig;
    }
  }
}

extern "C" void kernel_launch(void* const* d_in, const int* in_sizes, int n_in,
                              void* d_out, int out_size, void* d_ws, size_t ws_size,
                              hipStream_t stream) {
  const float* x     = (const float*)d_in[0];
  const float* Wqkv  = (const float*)d_in[1];
  const float* Wrk   = (const float*)d_in[2];
  const float* brk   = (const float*)d_in[3];
  const float* sscal = (const float*)d_in[4];
  const float* Wg    = (const float*)d_in[5];
  float* out = (float*)d_out;
  char* ws = (char*)d_ws;
  size_t off = 0;
  auto alloc = [&](size_t bytes) -> void* {
    void* p = ws + off;
    off += (bytes + 255) & ~(size_t)255;
    return p;
  };
  f16* x16     = (f16*)alloc((size_t)M_ROWS * DM * 2);
  f16* BtAll   = (f16*)alloc((size_t)NALLP * DM * 2);
  f16* CAll    = (f16*)alloc((size_t)M_ROWS * NALLP * 2);
  f16* q16     = (f16*)alloc((size_t)B_SZ * NH * T_SEQ * DH * 2);
  f16* k16     = (f16*)alloc((size_t)B_SZ * NKV * T_SEQ * DH * 2);
  f16* v16     = (f16*)alloc((size_t)B_SZ * NKV * T_SEQ * DH * 2);
  f16* vt16    = (f16*)alloc((size_t)B_SZ * NKV * T_SEQ * DH * 2);

  k_cvt<<<(M_ROWS * DM / 4 + 255) / 256, 256, 0, stream>>>(x, x16, M_ROWS * DM);
  k_cvt_t<<<dim3(DM / 32, NQKV / 32), 256, 0, stream>>>(Wqkv, BtAll, DM, NQKV);
  k_cvt_t<<<dim3(DM / 32, 64 / 32), 256, 0, stream>>>(Wrk, BtAll + (size_t)COL_RK * DM, DM, 64);
  k_cvt_t<<<dim3(DM / 32, DM / 32), 256, 0, stream>>>(Wg, BtAll + (size_t)COL_G * DM, DM, DM);

  k_gemm8<<<dim3(38, 16), 256, 0, stream>>>(x16, BtAll, CAll);

  k_postproc<<<M_ROWS, 256, 0, stream>>>(CAll, brk, sscal, q16, k16, v16);
  k_vt<<<dim3(T_SEQ / 32, DH / 32, B_SZ * NKV), 256, 0, stream>>>(v16, vt16);

  k_attn<<<dim3(T_SEQ / 64, NH, B_SZ), 256, 0, stream>>>(q16, k16, vt16, CAll, out);
}